// Round 5
// baseline (1049.377 us; speedup 1.0000x reference)
//
#include <hip/hip_runtime.h>

#define N_PTS 131072
#define NSEG 128

typedef unsigned short u16;
typedef __attribute__((ext_vector_type(8))) short short8;
typedef __attribute__((ext_vector_type(8))) unsigned short ushort8;
typedef __attribute__((ext_vector_type(4))) float f32x4;

__device__ __forceinline__ float b2f(u16 u){union{unsigned v;float f;}x;x.v=((unsigned)u)<<16;return x.f;}
__device__ __forceinline__ u16 f2b(float f){unsigned u=__float_as_uint(f);u+=0x7FFFu+((u>>16)&1u);return (u16)(u>>16);}

// zero both parities of segment accumulators (256 threads: 2*128 each)
__global__ void k_zero(float* __restrict__ a, float* __restrict__ w){
  a[threadIdx.x]=0.f; w[threadIdx.x]=0.f;
}

// pack 18 weight matrices, transposed bf16: Wf[mat][n*128+k]
__global__ __launch_bounds__(256) void k_wpack(const float* __restrict__ Wr,
    const float* __restrict__ convW, const float* __restrict__ outW, u16* __restrict__ Wf){
  int mat=blockIdx.x;
  const float* W=(mat<4)?(Wr+mat*16384):(mat<16)?(convW+(mat-4)*16384):(outW+(mat-16)*16384);
  u16* dst=Wf+mat*16384;
  for(int t=threadIdx.x;t<16384;t+=256){ int n=t>>7,k=t&127; dst[t]=f2b(W[k*128+n]); }
}

// ---- shared epilogue: logit -> exp -> L, per-segment-run atomics into accZ/accW ----
__device__ __forceinline__ void logit_epilogue(int tid,int row0,
    const float* rowL,float attb0,const float* __restrict__ wp,
    const int* __restrict__ seg,float* __restrict__ L,
    float* eS,float* swS,int* sgS,float* __restrict__ cZ,float* __restrict__ cW){
  if (tid<128){
    int r=row0+tid;
    float l=rowL[tid]+rowL[128+tid]+rowL[256+tid]+rowL[384+tid]+attb0;
    float e=__expf(fminf(l,60.f));     // no max-sub: logits are O(3); clamp = overflow guard
    float sw=e*wp[r];
    L[r]=sw;
    eS[tid]=e; swS[tid]=sw; sgS[tid]=seg[r];
  }
  __syncthreads();
  if (tid<128){
    int s=sgS[tid];
    if (tid==0 || sgS[tid-1]!=s){      // segment-run leader: 1-3 per block
      float se=0.f, ss=0.f;
      for(int i=tid;i<128 && sgS[i]==s;i++){ se+=eS[i]; ss+=swS[i]; }
      atomicAdd(&cZ[s],se); atomicAdd(&cW[s],ss);
    }
  }
}

// ---------------- conv GEMM: T = norm-staged(X) @ Wf + b, with logit epilogue ----------------
// IN=2: stage relu(norm(Tb)).  IN=3: stage relu(norm(Tb)) + A0, write back A0 (new residual h).
// Always: write Tb (bf16, in-place), L + acc atomics; zero cM/cQ slice for the next chansum.
template<int IN>
__global__ __launch_bounds__(256) void k_conv(
    u16* __restrict__ Tb, float* __restrict__ A0,
    const u16* __restrict__ Wfm, const float* __restrict__ Bv,
    const float* __restrict__ attWl, const float* __restrict__ attbl,
    float* __restrict__ L, const int* __restrict__ seg, const float* __restrict__ wp,
    const float* __restrict__ pZ, const float* __restrict__ pW,
    const float* __restrict__ pM, const float* __restrict__ pQ,
    float* __restrict__ cZ, float* __restrict__ cW,
    float* __restrict__ cM, float* __restrict__ cQ){
  __shared__ u16 Xs[128*136];
  __shared__ float rowL[512];
  __shared__ float eS[128], swS[128];
  __shared__ int sgS[128];
  const int tid=threadIdx.x, wave=tid>>6, lane=tid&63, q=lane>>4, m16=lane&15;
  const int row0=blockIdx.x*128;

  if (tid<16){ cM[blockIdx.x*16+tid]=0.f; cQ[blockIdx.x*16+tid]=0.f; }

  const u16* Xb=Tb+(size_t)row0*128;
  #pragma unroll
  for(int i=0;i<8;i++){
    int e8=i*2048+tid*8; int rloc=e8>>7, c8=e8&127;
    ushort8 raw=*(const ushort8*)&Xb[rloc*128+c8];
    int gr=row0+rloc; int s=seg[gr];
    float Z=pZ[s], W=pW[s];
    float invd=1.f/fmaxf(W,fmaxf(1e-3f*Z,1e-30f));
    float sa=W*invd;
    float4 mn0=*(const float4*)&pM[s*128+c8];
    float4 mn1=*(const float4*)&pM[s*128+c8+4];
    float4 q0=*(const float4*)&pQ[s*128+c8];
    float4 q1=*(const float4*)&pQ[s*128+c8+4];
    float mn[8]={mn0.x,mn0.y,mn0.z,mn0.w,mn1.x,mn1.y,mn1.z,mn1.w};
    float qv[8]={q0.x,q0.y,q0.z,q0.w,q1.x,q1.y,q1.z,q1.w};
    float v[8];
    #pragma unroll
    for(int j=0;j<8;j++){
      float m=mn[j];
      v[j]=fmaxf((b2f(raw[j])-m)*rsqrtf(qv[j]+(sa-2.f)*m*m+1e-3f),0.f);
    }
    if (IN==3){
      float4 h0=*(const float4*)&A0[(size_t)gr*128+c8];
      float4 h1=*(const float4*)&A0[(size_t)gr*128+c8+4];
      v[0]+=h0.x;v[1]+=h0.y;v[2]+=h0.z;v[3]+=h0.w;
      v[4]+=h1.x;v[5]+=h1.y;v[6]+=h1.z;v[7]+=h1.w;
      float4 w0={v[0],v[1],v[2],v[3]}, w1={v[4],v[5],v[6],v[7]};
      *(float4*)&A0[(size_t)gr*128+c8]=w0;
      *(float4*)&A0[(size_t)gr*128+c8+4]=w1;
    }
    ushort8 ob;
    #pragma unroll
    for(int j=0;j<8;j++) ob[j]=f2b(v[j]);
    *(ushort8*)&Xs[rloc*136+c8]=ob;
  }

  short8 bfr[2][4];
  #pragma unroll
  for(int ct=0;ct<2;ct++){
    int n=wave*32+ct*16+m16;
    #pragma unroll
    for(int kc=0;kc<4;kc++) bfr[ct][kc]=*(const short8*)&Wfm[n*128+kc*32+q*8];
  }
  const int c0=wave*32+m16, c1=c0+16;
  const float bias0=Bv[c0], bias1=Bv[c1];
  const float aw0=attWl[c0], aw1=attWl[c1];
  __syncthreads();

  #pragma unroll
  for(int rt=0;rt<8;rt++){
    int r0=rt*16;
    short8 af[4];
    #pragma unroll
    for(int kc=0;kc<4;kc++) af[kc]=*(const short8*)&Xs[(r0+m16)*136+kc*32+q*8];
    f32x4 acc0={0.f,0.f,0.f,0.f},acc1={0.f,0.f,0.f,0.f};
    #pragma unroll
    for(int kc=0;kc<4;kc++){
      acc0=__builtin_amdgcn_mfma_f32_16x16x32_bf16(af[kc],bfr[0][kc],acc0,0,0,0);
      acc1=__builtin_amdgcn_mfma_f32_16x16x32_bf16(af[kc],bfr[1][kc],acc1,0,0,0);
    }
    #pragma unroll
    for(int t=0;t<4;t++){
      int rloc=r0+q*4+t;
      float v0=acc0[t]+bias0, v1=acc1[t]+bias1;
      size_t o=(size_t)(row0+rloc)*128;
      Tb[o+c0]=f2b(v0); Tb[o+c1]=f2b(v1);
      float p=v0*aw0+v1*aw1;
      p+=__shfl_xor(p,1,64); p+=__shfl_xor(p,2,64);
      p+=__shfl_xor(p,4,64); p+=__shfl_xor(p,8,64);
      if(m16==0) rowL[wave*128+rloc]=p;
    }
  }
  __syncthreads();
  logit_epilogue(tid,row0,rowL,attbl[0],wp,seg,L,eS,swS,sgS,cZ,cW);
}

// ---------------- chansum: a = L*invd inline; stats atomics; zero other-parity accs ----------------
template<bool WA>
__global__ __launch_bounds__(256) void k_chansum(const u16* __restrict__ Tb,
    const float* __restrict__ L, const int* __restrict__ seg,
    const float* __restrict__ pZ, const float* __restrict__ pW,
    float* __restrict__ cM, float* __restrict__ cQ,
    float* __restrict__ oZ, float* __restrict__ oW,
    float* __restrict__ a_out){
  if (blockIdx.x==0 && threadIdx.x<128){ oZ[threadIdx.x]=0.f; oW[threadIdx.x]=0.f; }
  const int base=blockIdx.x*128;
  const int c=threadIdx.x&127, half=threadIdx.x>>7;
  float sax=0.f,sax2=0.f,invd=0.f; int cur=-1;
  for(int rr=half;rr<128;rr+=2){
    int r=base+rr, s=seg[r];
    if(s!=cur){
      if(cur>=0){atomicAdd(&cM[cur*128+c],sax);atomicAdd(&cQ[cur*128+c],sax2);}
      sax=0.f;sax2=0.f;cur=s;
      float Z=pZ[s],W=pW[s];
      invd=1.f/fmaxf(W,fmaxf(1e-3f*Z,1e-30f));
    }
    float a=L[r]*invd;
    float xv=b2f(Tb[(size_t)r*128+c]);
    float ax=a*xv; sax+=ax; sax2+=ax*xv;
    if(WA && c==0) a_out[r]=a;
  }
  if(cur>=0){atomicAdd(&cM[cur*128+c],sax);atomicAdd(&cQ[cur*128+c],sax2);}
}

// ---------------- megain: in0 + 4 MLP layers + conv(0,0) + logit epilogue ----------------
__global__ __launch_bounds__(256) void k_megain(
    const float* __restrict__ x, const float* __restrict__ W0, const float* __restrict__ b0,
    const u16* __restrict__ Wf, const float* __restrict__ br, const float* __restrict__ cb0,
    const float* __restrict__ attW0, const float* __restrict__ attb0,
    float* __restrict__ A0, u16* __restrict__ Tb, float* __restrict__ L,
    const int* __restrict__ seg, const float* __restrict__ wp,
    float* __restrict__ cZ, float* __restrict__ cW,
    float* __restrict__ cM, float* __restrict__ cQ){
  __shared__ u16 buf[2*128*136];
  __shared__ float xs[384], w0S[384], b0S[128];
  __shared__ float rowL[512]; __shared__ float eS[128], swS[128]; __shared__ int sgS[128];
  const int tid=threadIdx.x, wave=tid>>6, lane=tid&63, q=lane>>4, m16=lane&15;
  const int row0=blockIdx.x*128;
  if (tid<16){ cM[blockIdx.x*16+tid]=0.f; cQ[blockIdx.x*16+tid]=0.f; }
  if (tid<96) ((float4*)xs)[tid]=((const float4*)(x+(size_t)row0*3))[tid];
  else if (tid<192) ((float4*)w0S)[tid-96]=((const float4*)W0)[tid-96];
  else if (tid<224) ((float4*)b0S)[tid-192]=((const float4*)b0)[tid-192];
  __syncthreads();
  for(int i=0;i<64;i++){
    int idx=i*256+tid; int r=idx>>7, c=idx&127;
    float acc=b0S[c]+xs[r*3]*w0S[c]+xs[r*3+1]*w0S[128+c]+xs[r*3+2]*w0S[256+c];
    acc=acc>0.f?acc:0.01f*acc;
    buf[r*136+c]=f2b(acc);
  }
  __syncthreads();
  const int c0=wave*32+m16, c1=c0+16;
  int sb=0;
  for(int l=0;l<4;l++){
    const u16* Wl=Wf+l*16384;
    const u16* src=buf+sb*17408;
    u16* dst=buf+(sb^1)*17408;
    short8 bfr[2][4];
    #pragma unroll
    for(int ct=0;ct<2;ct++){
      int n=wave*32+ct*16+m16;
      #pragma unroll
      for(int kc=0;kc<4;kc++) bfr[ct][kc]=*(const short8*)&Wl[n*128+kc*32+q*8];
    }
    float bias0=br[l*128+c0], bias1=br[l*128+c1];
    #pragma unroll
    for(int rt=0;rt<8;rt++){
      int r0=rt*16;
      short8 af[4];
      #pragma unroll
      for(int kc=0;kc<4;kc++) af[kc]=*(const short8*)&src[(r0+m16)*136+kc*32+q*8];
      f32x4 acc0={0.f,0.f,0.f,0.f},acc1={0.f,0.f,0.f,0.f};
      #pragma unroll
      for(int kc=0;kc<4;kc++){
        acc0=__builtin_amdgcn_mfma_f32_16x16x32_bf16(af[kc],bfr[0][kc],acc0,0,0,0);
        acc1=__builtin_amdgcn_mfma_f32_16x16x32_bf16(af[kc],bfr[1][kc],acc1,0,0,0);
      }
      #pragma unroll
      for(int t=0;t<4;t++){
        int rloc=r0+q*4+t;
        float v0=acc0[t]+bias0, v1=acc1[t]+bias1;
        v0=v0>0.f?v0:0.01f*v0; v1=v1>0.f?v1:0.01f*v1;
        dst[rloc*136+c0]=f2b(v0); dst[rloc*136+c1]=f2b(v1);
        if (l==3){
          size_t o=(size_t)(row0+rloc)*128;
          A0[o+c0]=v0; A0[o+c1]=v1;   // h residual base (fp32)
        }
      }
    }
    __syncthreads();
    sb^=1;
  }
  // conv(0,0) from buf[sb] -> Tb + logits
  {
    const u16* Wl=Wf+4*16384;
    const u16* src=buf+sb*17408;
    short8 bfr[2][4];
    #pragma unroll
    for(int ct=0;ct<2;ct++){
      int n=wave*32+ct*16+m16;
      #pragma unroll
      for(int kc=0;kc<4;kc++) bfr[ct][kc]=*(const short8*)&Wl[n*128+kc*32+q*8];
    }
    float bias0=cb0[c0], bias1=cb0[c1];
    float aw0=attW0[c0], aw1=attW0[c1];
    #pragma unroll
    for(int rt=0;rt<8;rt++){
      int r0=rt*16;
      short8 af[4];
      #pragma unroll
      for(int kc=0;kc<4;kc++) af[kc]=*(const short8*)&src[(r0+m16)*136+kc*32+q*8];
      f32x4 acc0={0.f,0.f,0.f,0.f},acc1={0.f,0.f,0.f,0.f};
      #pragma unroll
      for(int kc=0;kc<4;kc++){
        acc0=__builtin_amdgcn_mfma_f32_16x16x32_bf16(af[kc],bfr[0][kc],acc0,0,0,0);
        acc1=__builtin_amdgcn_mfma_f32_16x16x32_bf16(af[kc],bfr[1][kc],acc1,0,0,0);
      }
      #pragma unroll
      for(int t=0;t<4;t++){
        int rloc=r0+q*4+t;
        float v0=acc0[t]+bias0, v1=acc1[t]+bias1;
        size_t o=(size_t)(row0+rloc)*128;
        Tb[o+c0]=f2b(v0); Tb[o+c1]=f2b(v1);
        float p=v0*aw0+v1*aw1;
        p+=__shfl_xor(p,1,64); p+=__shfl_xor(p,2,64);
        p+=__shfl_xor(p,4,64); p+=__shfl_xor(p,8,64);
        if(m16==0) rowL[wave*128+rloc]=p;
      }
    }
  }
  __syncthreads();
  logit_epilogue(tid,row0,rowL,attb0[0],wp,seg,L,eS,swS,sgS,cZ,cW);
}

// ---------------- megaout: norm+res staging + out0(lrelu) + out1 -> Of ----------------
__global__ __launch_bounds__(256) void k_megaout(
    const u16* __restrict__ Tb, const float* __restrict__ A0,
    const u16* __restrict__ Wf16, const float* __restrict__ outb,
    const int* __restrict__ seg,
    const float* __restrict__ pZ, const float* __restrict__ pW,
    const float* __restrict__ pM, const float* __restrict__ pQ,
    float* __restrict__ Of){
  __shared__ u16 buf[2*128*136];
  const int tid=threadIdx.x, wave=tid>>6, lane=tid&63, q=lane>>4, m16=lane&15;
  const int row0=blockIdx.x*128;
  const u16* Xb=Tb+(size_t)row0*128;
  #pragma unroll
  for(int i=0;i<8;i++){
    int e8=i*2048+tid*8; int rloc=e8>>7, c8=e8&127;
    ushort8 raw=*(const ushort8*)&Xb[rloc*128+c8];
    int gr=row0+rloc; int s=seg[gr];
    float Z=pZ[s], W=pW[s];
    float invd=1.f/fmaxf(W,fmaxf(1e-3f*Z,1e-30f));
    float sa=W*invd;
    float4 mn0=*(const float4*)&pM[s*128+c8];
    float4 mn1=*(const float4*)&pM[s*128+c8+4];
    float4 q0=*(const float4*)&pQ[s*128+c8];
    float4 q1=*(const float4*)&pQ[s*128+c8+4];
    float mn[8]={mn0.x,mn0.y,mn0.z,mn0.w,mn1.x,mn1.y,mn1.z,mn1.w};
    float qv[8]={q0.x,q0.y,q0.z,q0.w,q1.x,q1.y,q1.z,q1.w};
    float4 h0=*(const float4*)&A0[(size_t)gr*128+c8];
    float4 h1=*(const float4*)&A0[(size_t)gr*128+c8+4];
    float hv[8]={h0.x,h0.y,h0.z,h0.w,h1.x,h1.y,h1.z,h1.w};
    ushort8 ob;
    #pragma unroll
    for(int j=0;j<8;j++){
      float m=mn[j];
      float v=fmaxf((b2f(raw[j])-m)*rsqrtf(qv[j]+(sa-2.f)*m*m+1e-3f),0.f)+hv[j];
      ob[j]=f2b(v);
    }
    *(ushort8*)&buf[rloc*136+c8]=ob;
  }
  __syncthreads();
  const int c0=wave*32+m16, c1=c0+16;
  // out0: lrelu -> buf[1]
  {
    const u16* Wl=Wf16;
    u16* dst=buf+17408;
    short8 bfr[2][4];
    #pragma unroll
    for(int ct=0;ct<2;ct++){
      int n=wave*32+ct*16+m16;
      #pragma unroll
      for(int kc=0;kc<4;kc++) bfr[ct][kc]=*(const short8*)&Wl[n*128+kc*32+q*8];
    }
    float bias0=outb[c0], bias1=outb[c1];
    #pragma unroll
    for(int rt=0;rt<8;rt++){
      int r0=rt*16;
      short8 af[4];
      #pragma unroll
      for(int kc=0;kc<4;kc++) af[kc]=*(const short8*)&buf[(r0+m16)*136+kc*32+q*8];
      f32x4 acc0={0.f,0.f,0.f,0.f},acc1={0.f,0.f,0.f,0.f};
      #pragma unroll
      for(int kc=0;kc<4;kc++){
        acc0=__builtin_amdgcn_mfma_f32_16x16x32_bf16(af[kc],bfr[0][kc],acc0,0,0,0);
        acc1=__builtin_amdgcn_mfma_f32_16x16x32_bf16(af[kc],bfr[1][kc],acc1,0,0,0);
      }
      #pragma unroll
      for(int t=0;t<4;t++){
        int rloc=r0+q*4+t;
        float v0=acc0[t]+bias0, v1=acc1[t]+bias1;
        v0=v0>0.f?v0:0.01f*v0; v1=v1>0.f?v1:0.01f*v1;
        dst[rloc*136+c0]=f2b(v0); dst[rloc*136+c1]=f2b(v1);
      }
    }
  }
  __syncthreads();
  // out1 -> Of
  {
    const u16* Wl=Wf16+16384;
    const u16* src=buf+17408;
    short8 bfr[2][4];
    #pragma unroll
    for(int ct=0;ct<2;ct++){
      int n=wave*32+ct*16+m16;
      #pragma unroll
      for(int kc=0;kc<4;kc++) bfr[ct][kc]=*(const short8*)&Wl[n*128+kc*32+q*8];
    }
    float bias0=outb[128+c0], bias1=outb[128+c1];
    #pragma unroll
    for(int rt=0;rt<8;rt++){
      int r0=rt*16;
      short8 af[4];
      #pragma unroll
      for(int kc=0;kc<4;kc++) af[kc]=*(const short8*)&src[(r0+m16)*136+kc*32+q*8];
      f32x4 acc0={0.f,0.f,0.f,0.f},acc1={0.f,0.f,0.f,0.f};
      #pragma unroll
      for(int kc=0;kc<4;kc++){
        acc0=__builtin_amdgcn_mfma_f32_16x16x32_bf16(af[kc],bfr[0][kc],acc0,0,0,0);
        acc1=__builtin_amdgcn_mfma_f32_16x16x32_bf16(af[kc],bfr[1][kc],acc1,0,0,0);
      }
      #pragma unroll
      for(int t=0;t<4;t++){
        int rloc=r0+q*4+t;
        size_t o=(size_t)(row0+rloc)*128;
        Of[o+c0]=acc0[t]+bias0;
        Of[o+c1]=acc1[t]+bias1;
      }
    }
  }
}

// ---------------- launch ----------------
extern "C" void kernel_launch(void* const* d_in, const int* in_sizes, int n_in,
                              void* d_out, int out_size, void* d_ws, size_t ws_size,
                              hipStream_t stream){
  const float* x     = (const float*)d_in[0];
  const int*   seg   = (const int*)d_in[1];
  const float* wp    = (const float*)d_in[2];
  const float* Win0  = (const float*)d_in[3];
  const float* bin0  = (const float*)d_in[4];
  const float* Wr    = (const float*)d_in[5];
  const float* br    = (const float*)d_in[6];
  const float* convW = (const float*)d_in[7];
  const float* convb = (const float*)d_in[8];
  const float* attW  = (const float*)d_in[9];
  const float* attb  = (const float*)d_in[10];
  const float* outW  = (const float*)d_in[11];
  const float* outb  = (const float*)d_in[12];

  // ws layout (~97.3 MB; round-2 proved ws >= 128.5 MB)
  float* A0     = (float*)d_ws;                    // residual h fp32 (64 MB)
  u16*   Tb     = (u16*)(A0 + (size_t)N_PTS*128);  // bf16 activations (32 MB)
  float* L      = (float*)(Tb + (size_t)N_PTS*128);// e*wp per row (0.5 MB)
  float* accZ   = L + N_PTS;                       // [2][128]
  float* accW   = accZ + 256;                      // [2][128]
  float* statsM = accW + 256;                      // [2][16384]
  float* statsQ = statsM + 32768;                  // [2][16384]
  u16*   Wf     = (u16*)(statsQ + 32768);          // 18 packed matrices

  float* Of    = (float*)d_out;
  float* a_out = (float*)d_out + (size_t)N_PTS*128;

  const int GB = N_PTS/128;   // 1024 blocks

  k_zero<<<1,256,0,stream>>>(accZ, accW);
  k_wpack<<<18,256,0,stream>>>(Wr, convW, outW, Wf);
  // G_0 (parity 0): adds accZ[0]/accW[0], zeroes statsM[0]/statsQ[0]
  k_megain<<<GB,256,0,stream>>>(x, Win0, bin0, Wf, br, convb, attW, attb,
                                A0, Tb, L, seg, wp,
                                accZ, accW, statsM, statsQ);

  for(int j=0;j<12;j++){
    int p=j&1, p1=1-p;
    float* zP=accZ+p*128;  float* wP=accW+p*128;
    float* mP=statsM+(size_t)p*16384;  float* qP=statsQ+(size_t)p*16384;
    float* zO=accZ+p1*128; float* wO=accW+p1*128;
    float* mO=statsM+(size_t)p1*16384; float* qO=statsQ+(size_t)p1*16384;
    if (j==11)
      k_chansum<true><<<GB,256,0,stream>>>(Tb,L,seg,zP,wP,mP,qP,zO,wO,a_out);
    else
      k_chansum<false><<<GB,256,0,stream>>>(Tb,L,seg,zP,wP,mP,qP,zO,wO,nullptr);
    if (j<11){
      const u16* Wm = Wf + (size_t)(5+j)*16384;     // matrix for T_{j+1}
      const float* bias = convb + (j+1)*128;
      const float* aWl  = attW + (j+1)*128;
      const float* abl  = attb + (j+1);
      if ((j+1)&1)  // inner conv 2: stage relu(norm)
        k_conv<2><<<GB,256,0,stream>>>(Tb,nullptr,Wm,bias,aWl,abl,L,seg,wp,
                                       zP,wP,mP,qP, zO,wO,mO,qO);
      else          // first conv of next ResBlock: stage relu(norm)+res, update h
        k_conv<3><<<GB,256,0,stream>>>(Tb,A0,Wm,bias,aWl,abl,L,seg,wp,
                                       zP,wP,mP,qP, zO,wO,mO,qO);
    }
  }
  // final: stats parity 1 (from chansum_11)
  k_megaout<<<GB,256,0,stream>>>(Tb, A0, Wf+(size_t)16*16384, outb, seg,
                                 accZ+128, accW+128, statsM+16384, statsQ+16384, Of);
}

// Round 6
// 935.917 us; speedup vs baseline: 1.1212x; 1.1212x over previous
//
#include <hip/hip_runtime.h>

#define N_PTS 131072
#define NSEG 128
#define SW 132   // LDS row stride in u16 (128 + 4 pad)

typedef unsigned short u16;
typedef __attribute__((ext_vector_type(8))) short short8;
typedef __attribute__((ext_vector_type(8))) unsigned short ushort8;
typedef __attribute__((ext_vector_type(4))) float f32x4;

__device__ __forceinline__ float b2f(u16 u){union{unsigned v;float f;}x;x.v=((unsigned)u)<<16;return x.f;}
__device__ __forceinline__ u16 f2b(float f){unsigned u=__float_as_uint(f);u+=0x7FFFu+((u>>16)&1u);return (u16)(u>>16);}

// zero stats parity 0 (conv_0's atomic target)
__global__ __launch_bounds__(256) void k_zero(float* __restrict__ M0, float* __restrict__ Q0,
                                              float* __restrict__ Z0, float* __restrict__ W0){
  int t = blockIdx.x * 256 + threadIdx.x;   // 64 blocks -> 16384
  M0[t] = 0.f; Q0[t] = 0.f;
  if (t < 128) { Z0[t] = 0.f; W0[t] = 0.f; }
}

// pack 18 weight matrices, transposed bf16: Wf[mat][n*128+k]
__global__ __launch_bounds__(256) void k_wpack(const float* __restrict__ Wr,
    const float* __restrict__ convW, const float* __restrict__ outW, u16* __restrict__ Wf){
  int mat = blockIdx.x;
  const float* W = (mat<4) ? (Wr+mat*16384) : (mat<16) ? (convW+(mat-4)*16384) : (outW+(mat-16)*16384);
  u16* dst = Wf + mat*16384;
  for (int t = threadIdx.x; t < 16384; t += 256){ int n=t>>7,k=t&127; dst[t]=f2b(W[k*128+n]); }
}

// input layer: Tb = bf16(lrelu(x @ W0 + b0))
__global__ __launch_bounds__(256) void k_in0(const float* __restrict__ x,
    const float* __restrict__ W0, const float* __restrict__ b0, u16* __restrict__ Tb){
  int gid = blockIdx.x*256 + threadIdx.x;
  int n = gid>>7, c = gid&127;
  float acc = b0[c] + x[n*3]*W0[c] + x[n*3+1]*W0[128+c] + x[n*3+2]*W0[256+c];
  Tb[gid] = f2b(acc > 0.f ? acc : 0.01f*acc);
}

// ---------------- MLP GEMM: Tb = bf16(lrelu(Tb @ Wf + b)); WH: also A0 = fp32 value ----------------
template<bool WH>
__global__ __launch_bounds__(256) void k_mlp(u16* __restrict__ Tb, float* __restrict__ A0,
    const u16* __restrict__ Wfm, const float* __restrict__ Bv){
  __shared__ u16 Xs[128*SW];
  const int tid=threadIdx.x, wave=tid>>6, lane=tid&63, q=lane>>4, m16=lane&15;
  const int row0=blockIdx.x*128;
  const u16* Xb = Tb + (size_t)row0*128;
  #pragma unroll
  for (int i=0;i<8;i++){
    int e8=i*2048+tid*8; int rloc=e8>>7, c8=e8&127;
    *(ushort8*)&Xs[rloc*SW+c8] = *(const ushort8*)&Xb[rloc*128+c8];
  }
  // B frags: lane covers adjacent cols cA=wave*32+2*m16, cA+1
  short8 bfr[2][4];
  #pragma unroll
  for (int ct=0;ct<2;ct++){
    int n = wave*32 + 2*m16 + ct;
    #pragma unroll
    for (int kc=0;kc<4;kc++) bfr[ct][kc] = *(const short8*)&Wfm[n*128+kc*32+q*8];
  }
  const int cA = wave*32 + 2*m16;
  const float bias0=Bv[cA], bias1=Bv[cA+1];
  __syncthreads();
  #pragma unroll
  for (int rt=0;rt<8;rt++){
    int r0=rt*16;
    short8 af[4];
    #pragma unroll
    for (int kc=0;kc<4;kc++) af[kc] = *(const short8*)&Xs[(r0+m16)*SW+kc*32+q*8];
    f32x4 a0={0,0,0,0}, a1={0,0,0,0};
    #pragma unroll
    for (int kc=0;kc<4;kc++){
      a0=__builtin_amdgcn_mfma_f32_16x16x32_bf16(af[kc],bfr[0][kc],a0,0,0,0);
      a1=__builtin_amdgcn_mfma_f32_16x16x32_bf16(af[kc],bfr[1][kc],a1,0,0,0);
    }
    #pragma unroll
    for (int t=0;t<4;t++){
      int rloc=r0+q*4+t;
      float v0=a0[t]+bias0, v1=a1[t]+bias1;
      v0=v0>0.f?v0:0.01f*v0; v1=v1>0.f?v1:0.01f*v1;
      size_t wi=(size_t)(row0+rloc)*64 + wave*16 + m16;
      ((unsigned*)Tb)[wi] = (unsigned)f2b(v0) | ((unsigned)f2b(v1)<<16);
      if (WH) { float2 h={v0,v1}; ((float2*)A0)[wi]=h; }
    }
  }
}

// ---------------- fused conv: stage -> GEMM -> Tb + logits + unnormalized stats ----------------
// IN=1 plain copy; IN=2 norm+relu (prev stats); IN=3 norm+relu+residual, update A0.
// Writes: Tb, L (=e*wp), atomics into cZ/cW/cM/cQ (unnormalized); zeroes nZ/nW/nM/nQ.
template<int IN>
__global__ __launch_bounds__(256) void k_conv(u16* __restrict__ Tb, float* __restrict__ A0,
    const u16* __restrict__ Wfm, const float* __restrict__ Bv,
    const float* __restrict__ attWl, const float* __restrict__ attbl,
    float* __restrict__ L, const int* __restrict__ seg, const float* __restrict__ wp,
    const float* __restrict__ pZ, const float* __restrict__ pW,
    const float* __restrict__ pM, const float* __restrict__ pQ,
    float* __restrict__ cZ, float* __restrict__ cW,
    float* __restrict__ cM, float* __restrict__ cQ,
    float* __restrict__ nZ, float* __restrict__ nW,
    float* __restrict__ nM, float* __restrict__ nQ){
  __shared__ u16 Xs[128*SW];
  __shared__ float rowL[512];
  __shared__ float awpS[128], eSS[128];
  __shared__ int sgS[128];
  const int tid=threadIdx.x, wave=tid>>6, lane=tid&63, q=lane>>4, m16=lane&15;
  const int row0=blockIdx.x*128;

  // zero next-next parity (idle this kernel: safe)
  if (tid<16){ nM[blockIdx.x*16+tid]=0.f; nQ[blockIdx.x*16+tid]=0.f; }
  if (blockIdx.x==0 && tid<128){ nZ[tid]=0.f; nW[tid]=0.f; }

  const u16* Xb = Tb + (size_t)row0*128;
  #pragma unroll
  for (int i=0;i<8;i++){
    int e8=i*2048+tid*8; int rloc=e8>>7, c8=e8&127;
    ushort8 raw = *(const ushort8*)&Xb[rloc*128+c8];
    if (IN==1){
      *(ushort8*)&Xs[rloc*SW+c8] = raw;
    } else {
      int gr=row0+rloc, s=seg[gr];
      float Z=pZ[s], Wd=pW[s];
      float invd = 1.f/fmaxf(Wd, fmaxf(1e-3f*Z, 1e-30f));
      float sa = Wd*invd;
      float4 mn0=*(const float4*)&pM[s*128+c8];
      float4 mn1=*(const float4*)&pM[s*128+c8+4];
      float4 q0=*(const float4*)&pQ[s*128+c8];
      float4 q1=*(const float4*)&pQ[s*128+c8+4];
      float mn[8]={mn0.x,mn0.y,mn0.z,mn0.w,mn1.x,mn1.y,mn1.z,mn1.w};
      float qv[8]={q0.x,q0.y,q0.z,q0.w,q1.x,q1.y,q1.z,q1.w};
      float v[8];
      #pragma unroll
      for (int j=0;j<8;j++){
        float m=mn[j]*invd, m2=qv[j]*invd;
        v[j]=fmaxf((b2f(raw[j])-m)*rsqrtf(m2+(sa-2.f)*m*m+1e-3f),0.f);
      }
      if (IN==3){
        float4 h0=*(const float4*)&A0[(size_t)gr*128+c8];
        float4 h1=*(const float4*)&A0[(size_t)gr*128+c8+4];
        v[0]+=h0.x;v[1]+=h0.y;v[2]+=h0.z;v[3]+=h0.w;
        v[4]+=h1.x;v[5]+=h1.y;v[6]+=h1.z;v[7]+=h1.w;
        float4 w0={v[0],v[1],v[2],v[3]}, w1={v[4],v[5],v[6],v[7]};
        *(float4*)&A0[(size_t)gr*128+c8]=w0;
        *(float4*)&A0[(size_t)gr*128+c8+4]=w1;
      }
      ushort8 ob;
      #pragma unroll
      for (int j=0;j<8;j++) ob[j]=f2b(v[j]);
      *(ushort8*)&Xs[rloc*SW+c8]=ob;
    }
  }

  short8 bfr[2][4];
  #pragma unroll
  for (int ct=0;ct<2;ct++){
    int n = wave*32 + 2*m16 + ct;
    #pragma unroll
    for (int kc=0;kc<4;kc++) bfr[ct][kc]=*(const short8*)&Wfm[n*128+kc*32+q*8];
  }
  const int cA = wave*32 + 2*m16;
  const float bias0=Bv[cA], bias1=Bv[cA+1];
  const float aw0=attWl[cA], aw1=attWl[cA+1];
  __syncthreads();

  #pragma unroll
  for (int rt=0;rt<8;rt++){
    int r0=rt*16;
    short8 af[4];
    #pragma unroll
    for (int kc=0;kc<4;kc++) af[kc]=*(const short8*)&Xs[(r0+m16)*SW+kc*32+q*8];
    f32x4 a0={0,0,0,0}, a1={0,0,0,0};
    #pragma unroll
    for (int kc=0;kc<4;kc++){
      a0=__builtin_amdgcn_mfma_f32_16x16x32_bf16(af[kc],bfr[0][kc],a0,0,0,0);
      a1=__builtin_amdgcn_mfma_f32_16x16x32_bf16(af[kc],bfr[1][kc],a1,0,0,0);
    }
    #pragma unroll
    for (int t=0;t<4;t++){
      int rloc=r0+q*4+t;
      float v0=a0[t]+bias0, v1=a1[t]+bias1;
      ((unsigned*)Tb)[(size_t)(row0+rloc)*64 + wave*16 + m16] =
          (unsigned)f2b(v0) | ((unsigned)f2b(v1)<<16);
      float p=v0*aw0+v1*aw1;
      p+=__shfl_xor(p,1,64); p+=__shfl_xor(p,2,64);
      p+=__shfl_xor(p,4,64); p+=__shfl_xor(p,8,64);
      if (m16==0) rowL[wave*128+rloc]=p;
    }
  }
  __syncthreads();

  if (tid<128){
    int r=row0+tid;
    float l=rowL[tid]+rowL[128+tid]+rowL[256+tid]+rowL[384+tid]+attbl[0];
    float e=__expf(fminf(l,60.f));   // logits O(1); clamp = overflow guard only
    float sw=e*wp[r];
    L[r]=sw;
    eSS[tid]=e; awpS[tid]=sw; sgS[tid]=seg[r];
  }
  __syncthreads();
  if (tid<128){
    int s=sgS[tid];
    if (tid==0 || sgS[tid-1]!=s){  // run leader (1-3 per block)
      float se=0.f, ss=0.f;
      for (int i=tid;i<128 && sgS[i]==s;i++){ se+=eSS[i]; ss+=awpS[i]; }
      atomicAdd(&cZ[s],se); atomicAdd(&cW[s],ss);
    }
  }
  // unnormalized channel stats from just-written Tb (L2-hot, block-private rows)
  const int c=tid&127, half=tid>>7;
  float sax=0.f, sax2=0.f; int cur=-1;
  for (int rr=half; rr<128; rr+=2){
    int s=sgS[rr];
    if (s!=cur){
      if (cur>=0){ atomicAdd(&cM[cur*128+c],sax); atomicAdd(&cQ[cur*128+c],sax2); }
      sax=0.f; sax2=0.f; cur=s;
    }
    float xv=b2f(Tb[(size_t)(row0+rr)*128+c]);
    float ax=awpS[rr]*xv;
    sax+=ax; sax2+=ax*xv;
  }
  if (cur>=0){ atomicAdd(&cM[cur*128+c],sax); atomicAdd(&cQ[cur*128+c],sax2); }
}

// ---------------- megaout: norm+res + out0(lrelu) + out1 -> Of; a_out ----------------
__global__ __launch_bounds__(256) void k_megaout(const u16* __restrict__ Tb,
    const float* __restrict__ A0, const u16* __restrict__ Wf16, const float* __restrict__ outb,
    const int* __restrict__ seg, const float* __restrict__ L,
    const float* __restrict__ pZ, const float* __restrict__ pW,
    const float* __restrict__ pM, const float* __restrict__ pQ,
    float* __restrict__ Of, float* __restrict__ a_out){
  __shared__ u16 buf[2*128*SW];
  const int tid=threadIdx.x, wave=tid>>6, lane=tid&63, q=lane>>4, m16=lane&15;
  const int row0=blockIdx.x*128;
  const u16* Xb = Tb + (size_t)row0*128;
  #pragma unroll
  for (int i=0;i<8;i++){
    int e8=i*2048+tid*8; int rloc=e8>>7, c8=e8&127;
    ushort8 raw=*(const ushort8*)&Xb[rloc*128+c8];
    int gr=row0+rloc, s=seg[gr];
    float Z=pZ[s], Wd=pW[s];
    float invd=1.f/fmaxf(Wd, fmaxf(1e-3f*Z,1e-30f));
    float sa=Wd*invd;
    float4 mn0=*(const float4*)&pM[s*128+c8];
    float4 mn1=*(const float4*)&pM[s*128+c8+4];
    float4 q0=*(const float4*)&pQ[s*128+c8];
    float4 q1=*(const float4*)&pQ[s*128+c8+4];
    float mn[8]={mn0.x,mn0.y,mn0.z,mn0.w,mn1.x,mn1.y,mn1.z,mn1.w};
    float qv[8]={q0.x,q0.y,q0.z,q0.w,q1.x,q1.y,q1.z,q1.w};
    float4 h0=*(const float4*)&A0[(size_t)gr*128+c8];
    float4 h1=*(const float4*)&A0[(size_t)gr*128+c8+4];
    float hv[8]={h0.x,h0.y,h0.z,h0.w,h1.x,h1.y,h1.z,h1.w};
    ushort8 ob;
    #pragma unroll
    for (int j=0;j<8;j++){
      float m=mn[j]*invd, m2=qv[j]*invd;
      ob[j]=f2b(fmaxf((b2f(raw[j])-m)*rsqrtf(m2+(sa-2.f)*m*m+1e-3f),0.f)+hv[j]);
    }
    *(ushort8*)&buf[rloc*SW+c8]=ob;
  }
  if (tid<128){
    int r=row0+tid, s=seg[r];
    float invd=1.f/fmaxf(pW[s], fmaxf(1e-3f*pZ[s],1e-30f));
    a_out[r]=L[r]*invd;
  }
  __syncthreads();
  const int cA=wave*32+2*m16;
  // out0 (lrelu) -> buf[1]
  {
    u16* dst=buf+128*SW;
    short8 bfr[2][4];
    #pragma unroll
    for (int ct=0;ct<2;ct++){
      int n=wave*32+2*m16+ct;
      #pragma unroll
      for (int kc=0;kc<4;kc++) bfr[ct][kc]=*(const short8*)&Wf16[n*128+kc*32+q*8];
    }
    float bias0=outb[cA], bias1=outb[cA+1];
    #pragma unroll
    for (int rt=0;rt<8;rt++){
      int r0=rt*16;
      short8 af[4];
      #pragma unroll
      for (int kc=0;kc<4;kc++) af[kc]=*(const short8*)&buf[(r0+m16)*SW+kc*32+q*8];
      f32x4 a0={0,0,0,0}, a1={0,0,0,0};
      #pragma unroll
      for (int kc=0;kc<4;kc++){
        a0=__builtin_amdgcn_mfma_f32_16x16x32_bf16(af[kc],bfr[0][kc],a0,0,0,0);
        a1=__builtin_amdgcn_mfma_f32_16x16x32_bf16(af[kc],bfr[1][kc],a1,0,0,0);
      }
      #pragma unroll
      for (int t=0;t<4;t++){
        int rloc=r0+q*4+t;
        float v0=a0[t]+bias0, v1=a1[t]+bias1;
        v0=v0>0.f?v0:0.01f*v0; v1=v1>0.f?v1:0.01f*v1;
        dst[rloc*SW+2*m16+wave*32]=f2b(v0);
        dst[rloc*SW+2*m16+wave*32+1]=f2b(v1);
      }
    }
  }
  __syncthreads();
  // out1 -> Of (fp32)
  {
    const u16* src=buf+128*SW;
    short8 bfr[2][4];
    #pragma unroll
    for (int ct=0;ct<2;ct++){
      int n=wave*32+2*m16+ct;
      #pragma unroll
      for (int kc=0;kc<4;kc++) bfr[ct][kc]=*(const short8*)&Wf16[16384+n*128+kc*32+q*8];
    }
    float bias0=outb[128+cA], bias1=outb[128+cA+1];
    #pragma unroll
    for (int rt=0;rt<8;rt++){
      int r0=rt*16;
      short8 af[4];
      #pragma unroll
      for (int kc=0;kc<4;kc++) af[kc]=*(const short8*)&src[(r0+m16)*SW+kc*32+q*8];
      f32x4 a0={0,0,0,0}, a1={0,0,0,0};
      #pragma unroll
      for (int kc=0;kc<4;kc++){
        a0=__builtin_amdgcn_mfma_f32_16x16x32_bf16(af[kc],bfr[0][kc],a0,0,0,0);
        a1=__builtin_amdgcn_mfma_f32_16x16x32_bf16(af[kc],bfr[1][kc],a1,0,0,0);
      }
      #pragma unroll
      for (int t=0;t<4;t++){
        int rloc=r0+q*4+t;
        float2 o={a0[t]+bias0, a1[t]+bias1};
        ((float2*)Of)[(size_t)(row0+rloc)*64 + wave*16 + m16]=o;
      }
    }
  }
}

// ---------------- launch ----------------
extern "C" void kernel_launch(void* const* d_in, const int* in_sizes, int n_in,
                              void* d_out, int out_size, void* d_ws, size_t ws_size,
                              hipStream_t stream){
  const float* x     = (const float*)d_in[0];
  const int*   seg   = (const int*)d_in[1];
  const float* wp    = (const float*)d_in[2];
  const float* Win0  = (const float*)d_in[3];
  const float* bin0  = (const float*)d_in[4];
  const float* Wr    = (const float*)d_in[5];   // unused (packed)
  const float* br    = (const float*)d_in[6];
  const float* convW = (const float*)d_in[7];   // unused (packed)
  const float* convb = (const float*)d_in[8];
  const float* attW  = (const float*)d_in[9];
  const float* attb  = (const float*)d_in[10];
  const float* outW  = (const float*)d_in[11];  // unused (packed)
  const float* outb  = (const float*)d_in[12];

  float* A0 = (float*)d_ws;                       // residual h fp32 (64 MB)
  u16*   Tb = (u16*)(A0 + (size_t)N_PTS*128);     // bf16 activations (32 MB)
  float* L  = (float*)(Tb + (size_t)N_PTS*128);   // e*wp per row
  float* base = L + N_PTS;
  float* SZ[3], *SWt[3], *SM[3], *SQ[3];
  for (int p=0;p<3;p++){
    SZ[p]  = base + p*(128+128+16384+16384);
    SWt[p] = SZ[p] + 128;
    SM[p]  = SWt[p] + 128;
    SQ[p]  = SM[p] + 16384;
  }
  u16* Wf = (u16*)(base + 3*(128+128+16384+16384));

  float* Of    = (float*)d_out;
  float* a_out = (float*)d_out + (size_t)N_PTS*128;

  const int GB = N_PTS/128;   // 1024

  k_zero<<<64,256,0,stream>>>(SM[0],SQ[0],SZ[0],SWt[0]);
  k_wpack<<<18,256,0,stream>>>((const float*)d_in[5], convW, outW, Wf);
  k_in0<<<N_PTS*128/256,256,0,stream>>>(x, Win0, bin0, Tb);

  for (int i=0;i<3;i++)
    k_mlp<false><<<GB,256,0,stream>>>(Tb, nullptr, Wf+i*16384, br+i*128);
  k_mlp<true><<<GB,256,0,stream>>>(Tb, A0, Wf+3*16384, br+3*128);

  for (int j=0;j<12;j++){
    int wp_ = j%3, rp = (j+2)%3, np = (j+1)%3;   // write, read(prev=j-1), zero(next)
    const u16* Wm = Wf + (size_t)(4+j)*16384;
    if (j==0)
      k_conv<1><<<GB,256,0,stream>>>(Tb, nullptr, Wm, convb, attW, attb, L, seg, wp,
          nullptr,nullptr,nullptr,nullptr,
          SZ[wp_],SWt[wp_],SM[wp_],SQ[wp_], SZ[np],SWt[np],SM[np],SQ[np]);
    else if (j&1)
      k_conv<2><<<GB,256,0,stream>>>(Tb, nullptr, Wm, convb+j*128, attW+j*128, attb+j, L, seg, wp,
          SZ[rp],SWt[rp],SM[rp],SQ[rp],
          SZ[wp_],SWt[wp_],SM[wp_],SQ[wp_], SZ[np],SWt[np],SM[np],SQ[np]);
    else
      k_conv<3><<<GB,256,0,stream>>>(Tb, A0, Wm, convb+j*128, attW+j*128, attb+j, L, seg, wp,
          SZ[rp],SWt[rp],SM[rp],SQ[rp],
          SZ[wp_],SWt[wp_],SM[wp_],SQ[wp_], SZ[np],SWt[np],SM[np],SQ[np]);
  }

  // conv_11 wrote parity 11%3 = 2
  k_megaout<<<GB,256,0,stream>>>(Tb, A0, Wf+(size_t)16*16384, outb, seg, L,
                                 SZ[2],SWt[2],SM[2],SQ[2], Of, a_out);
}

// Round 7
// 727.302 us; speedup vs baseline: 1.4428x; 1.2868x over previous
//
#include <hip/hip_runtime.h>

#define N_PTS 131072
#define NSEG 128
#define SW 132   // LDS row stride in u16 (128 + 4 pad)

typedef unsigned short u16;
typedef __attribute__((ext_vector_type(8))) short short8;
typedef __attribute__((ext_vector_type(8))) unsigned short ushort8;
typedef __attribute__((ext_vector_type(4))) float f32x4;

__device__ __forceinline__ float b2f(u16 u){union{unsigned v;float f;}x;x.v=((unsigned)u)<<16;return x.f;}
__device__ __forceinline__ u16 f2b(float f){unsigned u=__float_as_uint(f);u+=0x7FFFu+((u>>16)&1u);return (u16)(u>>16);}

// zero stats parity 0
__global__ __launch_bounds__(256) void k_zero(float* __restrict__ M0, float* __restrict__ Q0,
                                              float* __restrict__ Z0, float* __restrict__ W0){
  int t = blockIdx.x * 256 + threadIdx.x;
  M0[t] = 0.f; Q0[t] = 0.f;
  if (t < 128) { Z0[t] = 0.f; W0[t] = 0.f; }
}

// pack 18 matrices transposed bf16 + fold attW: u[l][k]=sum_c bf16W[k][c]*attW[c], c0=b·attW+attb
__global__ __launch_bounds__(256) void k_wpack(const float* __restrict__ Wr,
    const float* __restrict__ convW, const float* __restrict__ outW,
    const float* __restrict__ attW, const float* __restrict__ attb,
    const float* __restrict__ convb,
    u16* __restrict__ Wf, float* __restrict__ uAtt, float* __restrict__ cAtt){
  int mat = blockIdx.x;
  const float* W = (mat<4) ? (Wr+mat*16384) : (mat<16) ? (convW+(mat-4)*16384) : (outW+(mat-16)*16384);
  u16* dst = Wf + mat*16384;
  for (int t = threadIdx.x; t < 16384; t += 256){ int n=t>>7,k=t&127; dst[t]=f2b(W[k*128+n]); }
  if (mat>=4 && mat<16){
    int l = mat-4;
    __syncthreads();
    int tid = threadIdx.x;
    if (tid < 128){
      float s = 0.f;
      for (int c=0;c<128;c++) s += b2f(dst[c*128+tid]) * attW[l*128+c];
      uAtt[l*128+tid] = s;
    } else if (tid == 128){
      float s = attb[l];
      for (int c=0;c<128;c++) s += convb[l*128+c] * attW[l*128+c];
      cAtt[l] = s;
    }
  }
}

// input layer: Tb = bf16(lrelu(x @ W0 + b0))
__global__ __launch_bounds__(256) void k_in0(const float* __restrict__ x,
    const float* __restrict__ W0, const float* __restrict__ b0, u16* __restrict__ Tb){
  int gid = blockIdx.x*256 + threadIdx.x;
  int n = gid>>7, c = gid&127;
  float acc = b0[c] + x[n*3]*W0[c] + x[n*3+1]*W0[128+c] + x[n*3+2]*W0[256+c];
  Tb[gid] = f2b(acc > 0.f ? acc : 0.01f*acc);
}

// ---------------- MLP GEMM: Tb = bf16(lrelu(Tb @ Wf + b)); WH: also A0 = fp32 ----------------
template<bool WH>
__global__ __launch_bounds__(256) void k_mlp(u16* __restrict__ Tb, float* __restrict__ A0,
    const u16* __restrict__ Wfm, const float* __restrict__ Bv){
  __shared__ u16 Xs[128*SW];
  const int tid=threadIdx.x, wave=tid>>6, lane=tid&63, q=lane>>4, m16=lane&15;
  const int row0=blockIdx.x*128;
  const u16* Xb = Tb + (size_t)row0*128;
  #pragma unroll
  for (int i=0;i<8;i++){
    int e8=i*2048+tid*8; int rloc=e8>>7, c8=e8&127;
    *(ushort8*)&Xs[rloc*SW+c8] = *(const ushort8*)&Xb[rloc*128+c8];
  }
  short8 bfr[2][4];
  #pragma unroll
  for (int ct=0;ct<2;ct++){
    int n = wave*32 + 2*m16 + ct;
    #pragma unroll
    for (int kc=0;kc<4;kc++) bfr[ct][kc] = *(const short8*)&Wfm[n*128+kc*32+q*8];
  }
  const int cA = wave*32 + 2*m16;
  const float bias0=Bv[cA], bias1=Bv[cA+1];
  __syncthreads();
  #pragma unroll
  for (int rt=0;rt<8;rt++){
    int r0=rt*16;
    short8 af[4];
    #pragma unroll
    for (int kc=0;kc<4;kc++) af[kc] = *(const short8*)&Xs[(r0+m16)*SW+kc*32+q*8];
    f32x4 a0={0,0,0,0}, a1={0,0,0,0};
    #pragma unroll
    for (int kc=0;kc<4;kc++){
      a0=__builtin_amdgcn_mfma_f32_16x16x32_bf16(af[kc],bfr[0][kc],a0,0,0,0);
      a1=__builtin_amdgcn_mfma_f32_16x16x32_bf16(af[kc],bfr[1][kc],a1,0,0,0);
    }
    #pragma unroll
    for (int t=0;t<4;t++){
      int rloc=r0+q*4+t;
      float v0=a0[t]+bias0, v1=a1[t]+bias1;
      v0=v0>0.f?v0:0.01f*v0; v1=v1>0.f?v1:0.01f*v1;
      size_t wi=(size_t)(row0+rloc)*64 + wave*16 + m16;
      ((unsigned*)Tb)[wi] = (unsigned)f2b(v0) | ((unsigned)f2b(v1)<<16);
      if (WH) { float2 h={v0,v1}; ((float2*)A0)[wi]=h; }
    }
  }
}

// ---------------- fused conv layer ----------------
// IN=1 plain copy; IN=2 norm+relu; IN=3 norm+relu+residual (updates A0).
// logit_r = x_r·u + c0 computed during staging; Z/Swp atomics pre-GEMM;
// channel stats accumulated in registers in the GEMM output loop.
template<int IN>
__global__ __launch_bounds__(256) void k_conv(u16* __restrict__ Tb, float* __restrict__ A0,
    const u16* __restrict__ Wfm, const float* __restrict__ Bv,
    const float* __restrict__ uL, const float* __restrict__ cL,
    float* __restrict__ L, const int* __restrict__ seg, const float* __restrict__ wp,
    const float* __restrict__ pZ, const float* __restrict__ pW,
    const float* __restrict__ pM, const float* __restrict__ pQ,
    float* __restrict__ cZ, float* __restrict__ cW,
    float* __restrict__ cM, float* __restrict__ cQ,
    float* __restrict__ nZ, float* __restrict__ nW,
    float* __restrict__ nM, float* __restrict__ nQ){
  __shared__ u16 Xs[128*SW];
  __shared__ float rowP[128];      // logit partial per row
  __shared__ float eS[128], aS[128];
  __shared__ int sgS[128];
  const int tid=threadIdx.x, wave=tid>>6, lane=tid&63, q=lane>>4, m16=lane&15;
  const int row0=blockIdx.x*128;

  // zero next parity (idle this layer)
  if (tid<16){ nM[blockIdx.x*16+tid]=0.f; nQ[blockIdx.x*16+tid]=0.f; }
  if (blockIdx.x==0 && tid<128){ nZ[tid]=0.f; nW[tid]=0.f; }

  // per-thread u slice (c8 fixed = (tid*8)&127)
  const int c8 = (tid*8)&127;
  float uv[8];
  { float4 u0=*(const float4*)&uL[c8]; float4 u1=*(const float4*)&uL[c8+4];
    uv[0]=u0.x;uv[1]=u0.y;uv[2]=u0.z;uv[3]=u0.w;uv[4]=u1.x;uv[5]=u1.y;uv[6]=u1.z;uv[7]=u1.w; }

  const u16* Xb = Tb + (size_t)row0*128;
  #pragma unroll
  for (int i=0;i<8;i++){
    int rloc = i*16 + (tid>>4);
    ushort8 raw = *(const ushort8*)&Xb[rloc*128+c8];
    float v[8];
    if (IN==1){
      #pragma unroll
      for (int j=0;j<8;j++) v[j]=b2f(raw[j]);
      *(ushort8*)&Xs[rloc*SW+c8] = raw;
    } else {
      int gr=row0+rloc, s=seg[gr];
      float Z=pZ[s], Wd=pW[s];
      float invd = 1.f/fmaxf(Wd, fmaxf(1e-3f*Z, 1e-30f));
      float sa = Wd*invd;
      float4 mn0=*(const float4*)&pM[s*128+c8];
      float4 mn1=*(const float4*)&pM[s*128+c8+4];
      float4 q0=*(const float4*)&pQ[s*128+c8];
      float4 q1=*(const float4*)&pQ[s*128+c8+4];
      float mn[8]={mn0.x,mn0.y,mn0.z,mn0.w,mn1.x,mn1.y,mn1.z,mn1.w};
      float qv[8]={q0.x,q0.y,q0.z,q0.w,q1.x,q1.y,q1.z,q1.w};
      #pragma unroll
      for (int j=0;j<8;j++){
        float m=mn[j]*invd, m2=qv[j]*invd;
        v[j]=fmaxf((b2f(raw[j])-m)*rsqrtf(m2+(sa-2.f)*m*m+1e-3f),0.f);
      }
      if (IN==3){
        float4 h0=*(const float4*)&A0[(size_t)gr*128+c8];
        float4 h1=*(const float4*)&A0[(size_t)gr*128+c8+4];
        v[0]+=h0.x;v[1]+=h0.y;v[2]+=h0.z;v[3]+=h0.w;
        v[4]+=h1.x;v[5]+=h1.y;v[6]+=h1.z;v[7]+=h1.w;
        float4 w0={v[0],v[1],v[2],v[3]}, w1={v[4],v[5],v[6],v[7]};
        *(float4*)&A0[(size_t)gr*128+c8]=w0;
        *(float4*)&A0[(size_t)gr*128+c8+4]=w1;
      }
      ushort8 ob;
      #pragma unroll
      for (int j=0;j<8;j++) ob[j]=f2b(v[j]);
      *(ushort8*)&Xs[rloc*SW+c8]=ob;
    }
    // logit partial for this row slice
    float p = v[0]*uv[0]+v[1]*uv[1]+v[2]*uv[2]+v[3]*uv[3]
            + v[4]*uv[4]+v[5]*uv[5]+v[6]*uv[6]+v[7]*uv[7];
    p += __shfl_xor(p,1,64); p += __shfl_xor(p,2,64);
    p += __shfl_xor(p,4,64); p += __shfl_xor(p,8,64);
    if (m16==0) rowP[rloc]=p;
  }

  short8 bfr[2][4];
  #pragma unroll
  for (int ct=0;ct<2;ct++){
    int n = wave*32 + 2*m16 + ct;
    #pragma unroll
    for (int kc=0;kc<4;kc++) bfr[ct][kc]=*(const short8*)&Wfm[n*128+kc*32+q*8];
  }
  const int cA = wave*32 + 2*m16;
  const float bias0=Bv[cA], bias1=Bv[cA+1];
  __syncthreads();   // Xs + rowP ready

  if (tid<128){
    int r=row0+tid;
    float l=rowP[tid]+cL[0];
    float e=__expf(fminf(l,60.f));   // logits O(1); clamp = overflow guard
    float sw=e*wp[r];
    L[r]=sw;
    eS[tid]=e; aS[tid]=sw; sgS[tid]=seg[r];
  }
  __syncthreads();   // eS/aS/sgS ready
  if (tid<128){
    int s=sgS[tid];
    if (tid==0 || sgS[tid-1]!=s){     // run leader (1-2 per block)
      float se=0.f, ss=0.f;
      for (int i=tid;i<128 && sgS[i]==s;i++){ se+=eS[i]; ss+=aS[i]; }
      atomicAdd(&cZ[s],se); atomicAdd(&cW[s],ss);
    }
  }

  const int s0=sgS[0], s127=sgS[127];
  const bool uni = (s0==s127);
  int cur = uni ? s0 : sgS[q*4];
  float sx0=0.f,sq0=0.f,sx1=0.f,sq1=0.f;

  #pragma unroll
  for (int rt=0;rt<8;rt++){
    int r0=rt*16;
    short8 af[4];
    #pragma unroll
    for (int kc=0;kc<4;kc++) af[kc]=*(const short8*)&Xs[(r0+m16)*SW+kc*32+q*8];
    f32x4 a0={0,0,0,0}, a1={0,0,0,0};
    #pragma unroll
    for (int kc=0;kc<4;kc++){
      a0=__builtin_amdgcn_mfma_f32_16x16x32_bf16(af[kc],bfr[0][kc],a0,0,0,0);
      a1=__builtin_amdgcn_mfma_f32_16x16x32_bf16(af[kc],bfr[1][kc],a1,0,0,0);
    }
    #pragma unroll
    for (int t=0;t<4;t++){
      int rloc=r0+q*4+t;
      float v0=a0[t]+bias0, v1=a1[t]+bias1;
      ((unsigned*)Tb)[(size_t)(row0+rloc)*64 + wave*16 + m16] =
          (unsigned)f2b(v0) | ((unsigned)f2b(v1)<<16);
      float a = aS[rloc];
      if (!uni){
        int s = sgS[rloc];
        if (s != cur){
          atomicAdd(&cM[cur*128+cA],sx0);  atomicAdd(&cQ[cur*128+cA],sq0);
          atomicAdd(&cM[cur*128+cA+1],sx1);atomicAdd(&cQ[cur*128+cA+1],sq1);
          sx0=sq0=sx1=sq1=0.f; cur=s;
        }
      }
      sx0 += a*v0; sq0 += a*v0*v0;
      sx1 += a*v1; sq1 += a*v1*v1;
    }
  }
  if (uni){
    sx0 += __shfl_xor(sx0,16,64); sx0 += __shfl_xor(sx0,32,64);
    sq0 += __shfl_xor(sq0,16,64); sq0 += __shfl_xor(sq0,32,64);
    sx1 += __shfl_xor(sx1,16,64); sx1 += __shfl_xor(sx1,32,64);
    sq1 += __shfl_xor(sq1,16,64); sq1 += __shfl_xor(sq1,32,64);
    if (q==0){
      atomicAdd(&cM[s0*128+cA],sx0);  atomicAdd(&cQ[s0*128+cA],sq0);
      atomicAdd(&cM[s0*128+cA+1],sx1);atomicAdd(&cQ[s0*128+cA+1],sq1);
    }
  } else {
    atomicAdd(&cM[cur*128+cA],sx0);  atomicAdd(&cQ[cur*128+cA],sq0);
    atomicAdd(&cM[cur*128+cA+1],sx1);atomicAdd(&cQ[cur*128+cA+1],sq1);
  }
}

// ---------------- megaout: norm+res + out0(lrelu) + out1 -> Of; a_out ----------------
__global__ __launch_bounds__(256) void k_megaout(const u16* __restrict__ Tb,
    const float* __restrict__ A0, const u16* __restrict__ Wf16, const float* __restrict__ outb,
    const int* __restrict__ seg, const float* __restrict__ L,
    const float* __restrict__ pZ, const float* __restrict__ pW,
    const float* __restrict__ pM, const float* __restrict__ pQ,
    float* __restrict__ Of, float* __restrict__ a_out){
  __shared__ u16 buf[2*128*SW];
  const int tid=threadIdx.x, wave=tid>>6, lane=tid&63, q=lane>>4, m16=lane&15;
  const int row0=blockIdx.x*128;
  const u16* Xb = Tb + (size_t)row0*128;
  #pragma unroll
  for (int i=0;i<8;i++){
    int e8=i*2048+tid*8; int rloc=e8>>7, c8=e8&127;
    ushort8 raw=*(const ushort8*)&Xb[rloc*128+c8];
    int gr=row0+rloc, s=seg[gr];
    float Z=pZ[s], Wd=pW[s];
    float invd=1.f/fmaxf(Wd, fmaxf(1e-3f*Z,1e-30f));
    float sa=Wd*invd;
    float4 mn0=*(const float4*)&pM[s*128+c8];
    float4 mn1=*(const float4*)&pM[s*128+c8+4];
    float4 q0=*(const float4*)&pQ[s*128+c8];
    float4 q1=*(const float4*)&pQ[s*128+c8+4];
    float mn[8]={mn0.x,mn0.y,mn0.z,mn0.w,mn1.x,mn1.y,mn1.z,mn1.w};
    float qv[8]={q0.x,q0.y,q0.z,q0.w,q1.x,q1.y,q1.z,q1.w};
    float4 h0=*(const float4*)&A0[(size_t)gr*128+c8];
    float4 h1=*(const float4*)&A0[(size_t)gr*128+c8+4];
    float hv[8]={h0.x,h0.y,h0.z,h0.w,h1.x,h1.y,h1.z,h1.w};
    ushort8 ob;
    #pragma unroll
    for (int j=0;j<8;j++){
      float m=mn[j]*invd, m2=qv[j]*invd;
      ob[j]=f2b(fmaxf((b2f(raw[j])-m)*rsqrtf(m2+(sa-2.f)*m*m+1e-3f),0.f)+hv[j]);
    }
    *(ushort8*)&buf[rloc*SW+c8]=ob;
  }
  if (tid<128){
    int r=row0+tid, s=seg[r];
    float invd=1.f/fmaxf(pW[s], fmaxf(1e-3f*pZ[s],1e-30f));
    a_out[r]=L[r]*invd;
  }
  __syncthreads();
  const int cA=wave*32+2*m16;
  {
    u16* dst=buf+128*SW;
    short8 bfr[2][4];
    #pragma unroll
    for (int ct=0;ct<2;ct++){
      int n=wave*32+2*m16+ct;
      #pragma unroll
      for (int kc=0;kc<4;kc++) bfr[ct][kc]=*(const short8*)&Wf16[n*128+kc*32+q*8];
    }
    float bias0=outb[cA], bias1=outb[cA+1];
    #pragma unroll
    for (int rt=0;rt<8;rt++){
      int r0=rt*16;
      short8 af[4];
      #pragma unroll
      for (int kc=0;kc<4;kc++) af[kc]=*(const short8*)&buf[(r0+m16)*SW+kc*32+q*8];
      f32x4 a0={0,0,0,0}, a1={0,0,0,0};
      #pragma unroll
      for (int kc=0;kc<4;kc++){
        a0=__builtin_amdgcn_mfma_f32_16x16x32_bf16(af[kc],bfr[0][kc],a0,0,0,0);
        a1=__builtin_amdgcn_mfma_f32_16x16x32_bf16(af[kc],bfr[1][kc],a1,0,0,0);
      }
      #pragma unroll
      for (int t=0;t<4;t++){
        int rloc=r0+q*4+t;
        float v0=a0[t]+bias0, v1=a1[t]+bias1;
        v0=v0>0.f?v0:0.01f*v0; v1=v1>0.f?v1:0.01f*v1;
        dst[rloc*SW+cA]=f2b(v0);
        dst[rloc*SW+cA+1]=f2b(v1);
      }
    }
  }
  __syncthreads();
  {
    const u16* src=buf+128*SW;
    short8 bfr[2][4];
    #pragma unroll
    for (int ct=0;ct<2;ct++){
      int n=wave*32+2*m16+ct;
      #pragma unroll
      for (int kc=0;kc<4;kc++) bfr[ct][kc]=*(const short8*)&Wf16[16384+n*128+kc*32+q*8];
    }
    float bias0=outb[128+cA], bias1=outb[128+cA+1];
    #pragma unroll
    for (int rt=0;rt<8;rt++){
      int r0=rt*16;
      short8 af[4];
      #pragma unroll
      for (int kc=0;kc<4;kc++) af[kc]=*(const short8*)&src[(r0+m16)*SW+kc*32+q*8];
      f32x4 a0={0,0,0,0}, a1={0,0,0,0};
      #pragma unroll
      for (int kc=0;kc<4;kc++){
        a0=__builtin_amdgcn_mfma_f32_16x16x32_bf16(af[kc],bfr[0][kc],a0,0,0,0);
        a1=__builtin_amdgcn_mfma_f32_16x16x32_bf16(af[kc],bfr[1][kc],a1,0,0,0);
      }
      #pragma unroll
      for (int t=0;t<4;t++){
        int rloc=r0+q*4+t;
        float2 o={a0[t]+bias0, a1[t]+bias1};
        ((float2*)Of)[(size_t)(row0+rloc)*64 + wave*16 + m16]=o;
      }
    }
  }
}

// ---------------- launch ----------------
extern "C" void kernel_launch(void* const* d_in, const int* in_sizes, int n_in,
                              void* d_out, int out_size, void* d_ws, size_t ws_size,
                              hipStream_t stream){
  const float* x     = (const float*)d_in[0];
  const int*   seg   = (const int*)d_in[1];
  const float* wp    = (const float*)d_in[2];
  const float* Win0  = (const float*)d_in[3];
  const float* bin0  = (const float*)d_in[4];
  const float* Wr    = (const float*)d_in[5];
  const float* br    = (const float*)d_in[6];
  const float* convW = (const float*)d_in[7];
  const float* convb = (const float*)d_in[8];
  const float* attW  = (const float*)d_in[9];
  const float* attb  = (const float*)d_in[10];
  const float* outW  = (const float*)d_in[11];
  const float* outb  = (const float*)d_in[12];

  float* A0 = (float*)d_ws;                       // residual h fp32 (64 MB)
  u16*   Tb = (u16*)(A0 + (size_t)N_PTS*128);     // bf16 activations (32 MB)
  float* L  = (float*)(Tb + (size_t)N_PTS*128);   // e*wp per row
  float* base = L + N_PTS;
  float* SZ[3], *SWt[3], *SM[3], *SQ[3];
  for (int p=0;p<3;p++){
    SZ[p]  = base + p*(128+128+16384+16384);
    SWt[p] = SZ[p] + 128;
    SM[p]  = SWt[p] + 128;
    SQ[p]  = SM[p] + 16384;
  }
  float* uAtt = base + 3*(128+128+16384+16384);   // [12][128]
  float* cAtt = uAtt + 12*128;                    // [12]
  u16*   Wf   = (u16*)(cAtt + 16);

  float* Of    = (float*)d_out;
  float* a_out = (float*)d_out + (size_t)N_PTS*128;

  const int GB = N_PTS/128;   // 1024

  k_zero<<<64,256,0,stream>>>(SM[0],SQ[0],SZ[0],SWt[0]);
  k_wpack<<<18,256,0,stream>>>(Wr, convW, outW, attW, attb, convb, Wf, uAtt, cAtt);
  k_in0<<<N_PTS*128/256,256,0,stream>>>(x, Win0, bin0, Tb);

  for (int i=0;i<3;i++)
    k_mlp<false><<<GB,256,0,stream>>>(Tb, nullptr, Wf+i*16384, br+i*128);
  k_mlp<true><<<GB,256,0,stream>>>(Tb, A0, Wf+3*16384, br+3*128);

  for (int j=0;j<12;j++){
    int wp_ = j%3, rp = (j+2)%3, np = (j+1)%3;
    const u16* Wm = Wf + (size_t)(4+j)*16384;
    const float* uj = uAtt + j*128;
    const float* cj = cAtt + j;
    if (j==0)
      k_conv<1><<<GB,256,0,stream>>>(Tb, nullptr, Wm, convb, uj, cj, L, seg, wp,
          nullptr,nullptr,nullptr,nullptr,
          SZ[wp_],SWt[wp_],SM[wp_],SQ[wp_], SZ[np],SWt[np],SM[np],SQ[np]);
    else if (j&1)
      k_conv<2><<<GB,256,0,stream>>>(Tb, nullptr, Wm, convb+j*128, uj, cj, L, seg, wp,
          SZ[rp],SWt[rp],SM[rp],SQ[rp],
          SZ[wp_],SWt[wp_],SM[wp_],SQ[wp_], SZ[np],SWt[np],SM[np],SQ[np]);
    else
      k_conv<3><<<GB,256,0,stream>>>(Tb, A0, Wm, convb+j*128, uj, cj, L, seg, wp,
          SZ[rp],SWt[rp],SM[rp],SQ[rp],
          SZ[wp_],SWt[wp_],SM[wp_],SQ[wp_], SZ[np],SWt[np],SM[np],SQ[np]);
  }

  // conv_11 wrote parity 11%3 = 2
  k_megaout<<<GB,256,0,stream>>>(Tb, A0, Wf+(size_t)16*16384, outb, seg, L,
                                 SZ[2],SWt[2],SM[2],SQ[2], Of, a_out);
}